// Round 8
// baseline (191.247 us; speedup 1.0000x reference)
//
#include <hip/hip_runtime.h>
#include <hip/hip_bf16.h>
#include <math.h>

// Problem constants
#define J   21
#define NH  7
#define H   4
#define HD  64
#define ALPHA 0.2f
#define LOG2E 1.44269504f

// LDS strides (in elements)
#define JPA  40    // x_bf row stride (shorts)
#define JPT  24    // h_t / h2_t row stride (shorts)
#define HPR  72    // hpB per-head row stride (shorts); 72 sh = 144 B: 16B-aligned rows,
                   // stride 36 dwords == 4 mod 32 -> 2-way bank aliasing (free, m136)
#define HSLOT 1584 // per-head slot stride in region A (shorts) = max(h_t 64*24=1536, hpB 22*72=1584)
#define F12S 32    // f1/f2 per-head stride (floats); slots 21..31 = -inf pads
#define ROW2 68    // h2 fp32 row stride (floats)
#define WHTL_F 4012 // whtL base (floats): WhT staged copy [1024 f] + 16 f zero tail pad

// LDS map (floats), total 5052 f = 20208 B -> rounds to 20480 = 163840/8 -> 8 blocks/CU:
//   [0,3168)     region A (per-head slots of HSLOT=1584 shorts at w*1584):
//                s1 out: h_t head rows i=0..63 at w*1584 + i*24 (shorts); gap [1536,1584)
//                        per slot: first 8 shorts zeroed in s0 (s4 quad3 A-read spill of
//                        last h_t row)
//                s4 out (overlay, SAME head slot -> no cross-wave race; within-wave WAR
//                        solved by preloading all 4 A-frags before any write):
//                        hpB row r at w*1584 + r*72, r=0..21 (row 21 zeroed by col==5 lanes)
//                s5 out (overlay after mid-s5 barrier, all hpB reads drained):
//                        h2[21][ROW2] fp32 @ A+0 (1428 f); h2_t[64][JPT] shorts @ float 1432
//                        (ends 2200; s8 quad3 spill reads A[2200..2202) = finite leftovers x 0)
//   [3168,3608)  x_bf[22][JPA] shorts (s0: zero pass covers shorts [8,40) of rows 0..20 +
//                row 21; scatter covers [0,7); 21 threads zero short 7 -> ONE barrier);
//                dead after s1 -> f1o@[3168,3189), f2o@[3192,3224) overlay
//                (tail-s6 out / s8 in; f2o 21..31 = -inf, written by the tail waves)
//   [3608,3755)  xs_raw[147] fp32 (s0 out / s1b in)
//   [3756,3884)  f1[4][F12S] (s1b out / s4 in; NO barrier between: wave w writes AND reads
//                only head w's slots -> within-wave LDS in-order suffices)
//   [3884,4012)  f2[4][F12S] (same; 21..31 = -inf, set in s0)
//   [4012,5036)  whtL[2048 shorts]: WhT staged via global_load_lds in s0 (s1 B-frags)
//   [5036,5052)  zero tail pad: s1 quad3 b-reads overshoot whtL by <=48B; A-side k>=8 is
//                exact zero so any FINITE value is safe; must not be uninit (NaN/Inf x 0)
#define LDS_FLOATS 5052

typedef __attribute__((ext_vector_type(8))) short short8;
typedef __attribute__((ext_vector_type(4))) float floatx4;
typedef __attribute__((ext_vector_type(4))) unsigned uintx4;

typedef __attribute__((address_space(1))) const void gas_void;
typedef __attribute__((address_space(3))) void las_void;

static __device__ __forceinline__ short f2bf(float f) {          // RNE (preconv only)
    __hip_bfloat16 h = __float2bfloat16(f);
    return __builtin_bit_cast(short, h);
}
static __device__ __forceinline__ short hi16(float f) {          // truncating bf16 (cheap)
    return (short)(__builtin_bit_cast(unsigned, f) >> 16);
}
static __device__ __forceinline__ unsigned pack2hi(float lo, float hi) {
    return __builtin_amdgcn_perm(__builtin_bit_cast(unsigned, hi),
                                 __builtin_bit_cast(unsigned, lo), 0x07060302u);
}
static __device__ __forceinline__ float elu(float a) {
    return (a > 0.f) ? a : (__expf(a) - 1.f);
}

#if __has_builtin(__builtin_amdgcn_exp2f)
static __device__ __forceinline__ float exp2_fast(float x) { return __builtin_amdgcn_exp2f(x); }
#else
static __device__ __forceinline__ float exp2_fast(float x) { return exp2f(x); }
#endif
#if __has_builtin(__builtin_amdgcn_rcpf)
static __device__ __forceinline__ float rcp_fast(float x) { return __builtin_amdgcn_rcpf(x); }
#else
static __device__ __forceinline__ float rcp_fast(float x) { return 1.f / x; }
#endif

// ---- pre-kernel: bf16 weight tables + wha fusion + log2e-prescaled ao ----
// ws shorts: [0,16384)      WoT[n=64][k=256] = bf(Wo[k][n])
//            [16384,18432)  WhT[(h*64+d)][8] : n<7 -> bf(Wh[h][n][d]), n=7 -> 0
//            [18432,18560)  wha[h][2][8] fp32 : wha[h][s][n] = LOG2E * sum_d Wh[h][n][d]*ah[h][s*64+d]
//            [18560,18816)  aoS[128] fp32 = ao * LOG2E
__global__ void preconv(const float* __restrict__ Wo, const float* __restrict__ Wh,
                        const float* __restrict__ ah, const float* __restrict__ ao,
                        short* __restrict__ ws) {
    int t = blockIdx.x * 256 + threadIdx.x;
    if (t < 16384) {
        int n = t >> 8, k = t & 255;
        ws[t] = f2bf(Wo[k * HD + n]);
    } else if (t < 18432) {
        int i = t - 16384;
        int hh = i >> 9, d = (i >> 3) & 63, n = i & 7;
        ws[t] = (n < 7) ? f2bf(Wh[(hh * NH + n) * HD + d]) : (short)0;
    } else if (t < 18496) {
        int i = t - 18432;                 // 0..63
        int hh = i >> 4, s = (i >> 3) & 1, n = i & 7;
        float acc = 0.f;
        if (n < 7) {
            for (int d = 0; d < HD; d++)
                acc += Wh[(hh * NH + n) * HD + d] * ah[hh * 2 * HD + s * HD + d];
        }
        ((float*)(ws + 18432))[i] = acc * LOG2E;
    } else if (t < 18624) {
        int i = t - 18496;                 // 0..127
        ((float*)(ws + 18560))[i] = ao[i] * LOG2E;
    }
}

__global__ __launch_bounds__(256, 8)
void gat_kernel(const float* __restrict__ inp,
                const short* __restrict__ ws,   // WoT + WhT + wha + aoS
                float* __restrict__ out)
{
    __shared__ __align__(16) float smem[LDS_FLOATS];
    short* regA   = (short*)smem;                 // h_t / hpB / h2_t home
    float* h2     = smem;                         // [21][ROW2] fp32 (post mid-s5 overlay)
    short* h2_t   = (short*)(smem + 1432);        // [64][JPT]  (post mid-s5 overlay)
    float* f1o    = smem + 3168;                  // tail overlays of x_bf region
    float* f2o    = smem + 3192;
    float* f1     = smem + 3756;                  // [4][F12S]
    float* f2     = smem + 3884;                  // [4][F12S]
    short* whtL   = (short*)(smem + WHTL_F);      // [2048] staged WhT

    const short* WoT  = ws;
    const short* WhT  = ws + 16384;
    const float* whaF = (const float*)(ws + 18432);
    const float* aoS  = (const float*)(ws + 18560);

    const int t    = threadIdx.x;
    const int w    = t >> 6;          // wave = head = tile index
    const int lane = t & 63;
    const int quad = lane >> 4;
    const int col  = lane & 15;
    const int rc   = (16 + col < 21) ? (16 + col) : 21;   // clamped M1 row (row 21 zeroed)

    const size_t pair = blockIdx.x;
    const float* ip = inp + pair * (size_t)(J * NH);

    // ---- stage 0 (ONE barrier): issue input load + async WhT->LDS stage first (both
    //      latencies hide under the zero/pad writes; the barrier's vmcnt(0) drains the
    //      async stage). Zero pass covers only x_bf shorts [8,40) per row (+row 21) so
    //      the scatter (shorts [0,7)) and k=7 zeroing write disjoint addresses. ----
    float v = 0.f;
    if (t < J * NH) v = ip[t];
    __builtin_amdgcn_global_load_lds(
        (gas_void*)(WhT + (size_t)(w * 64 + lane) * 8),
        (las_void*)(whtL + w * 512), 16, 0, 0);

    {
        floatx4 z4 = {0.f, 0.f, 0.f, 0.f};
        if (t < 84) {                 // x_bf rows 0..20, shorts [8,40) = 4 float4/row
            int j = t >> 2, q = t & 3;
            *(floatx4*)(smem + 3168 + j * 20 + 4 + q * 4) = z4;
        } else if (t < 89) {          // x_bf row 21 entire (5 float4)
            *(floatx4*)(smem + 3168 + 420 + (t - 84) * 4) = z4;
        } else if (t < 105) {         // region-A slot gaps (s4 quad3 A-read spill), 4 f/head
            int i = t - 89;
            smem[(i >> 2) * (HSLOT / 2) + (1536 / 2) + (i & 3)] = 0.f;
        } else if (t < 149) {         // f2 -inf softmax pads 21..31, 4 heads
            int i = t - 105;
            int hh = i / 11, jj = i - hh * 11;
            f2[hh * F12S + 21 + jj] = -INFINITY;
        } else if (t < 165) {         // whtL finite tail pad (s1 quad3 b-read overshoot)
            smem[WHTL_F + 1024 + (t - 149)] = 0.f;
        }
    }
    if (t < J * NH) {                 // scatter: x_bf shorts [0,7) + xs_raw
        int j, k;
        if (t < 63)       { j = t / 3;        k = t % 3; }
        else if (t < 126) { j = (t - 63) / 3; k = 3 + (t - 63) % 3; }
        else              { j = t - 126;      k = 6; }
        ((short*)(smem + 3168))[j * JPA + k] = hi16(v);
        smem[3608 + t] = v;
    } else if (t < 168) {             // x_bf short 7 zero, rows 0..20
        ((short*)(smem + 3168))[(t - 147) * JPA + 7] = 0;
    }
    __syncthreads();                  // barrier #1

    // ---- stage 1 (MFMA): h = x[21x7pad32] @ Wh_head[7x64] -> h_t bf16 (B-layout, per-head
    //      slot at w*HSLOT), packed b64 writes. B-frags from whtL (LDS, staged in s0).
    //      1b (PER-WAVE): wave w computes head w's f1/f2 (lanes 0..20 -> f1, 21..41 -> f2).
    //      All s1->s4 dependencies (h_t, f1, f2) are wave-local -> NO barrier before s4. ----
    {
        const short* x_bf = (const short*)(smem + 3168);
        short8 xa0 = *(const short8*)(x_bf + col * JPA + quad * 8);
        short8 xa1 = *(const short8*)(x_bf + rc  * JPA + quad * 8);
        #pragma unroll
        for (int nt = 0; nt < 4; nt++) {
            short8 b = *(const short8*)(whtL + ((w * 64 + nt * 16 + col) << 3) + quad * 8);
            floatx4 z = {0.f, 0.f, 0.f, 0.f};
            floatx4 c0 = __builtin_amdgcn_mfma_f32_16x16x32_bf16(xa0, b, z, 0, 0, 0);
            floatx4 c1 = __builtin_amdgcn_mfma_f32_16x16x32_bf16(xa1, b, z, 0, 0, 0);
            short* colbase = regA + w * HSLOT + (nt * 16 + col) * JPT;
            *(uint2*)(colbase + quad * 4) =
                make_uint2(pack2hi(c0[0], c0[1]), pack2hi(c0[2], c0[3]));
            if (quad == 0)          // rows 16..19
                *(uint2*)(colbase + 16) =
                    make_uint2(pack2hi(c1[0], c1[1]), pack2hi(c1[2], c1[3]));
            else if (quad == 1)     // rows 20..23: row20 value, 21..23 zero
                *(uint2*)(colbase + 20) = make_uint2(pack2hi(c1[0], 0.f), 0u);
        }
        if (lane < 2 * J) {
            int wh = (lane >= J) ? 1 : 0;          // 0 -> f1, 1 -> f2
            int j  = lane - wh * J;
            const float* xr = smem + 3608;    // xs_raw
            float x0 = xr[j*3+0], x1 = xr[j*3+1], x2 = xr[j*3+2];
            float x3 = xr[63+j*3+0], x4 = xr[63+j*3+1], x5 = xr[63+j*3+2];
            float x6 = xr[126+j];
            const float* wp = whaF + w * 16 + wh * 8;
            float r = x0*wp[0] + x1*wp[1] + x2*wp[2] + x3*wp[3]
                    + x4*wp[4] + x5*wp[5] + x6*wp[6];
            (wh ? f2 : f1)[w * F12S + j] = r;
        }
    }
    // NO barrier: s4 consumes only wave-local LDS state (see s1 comment).

    // ---- stage 4 (MFMA + register softmax): no valid-masking (f2 pads -inf -> exp2 -> 0).
    //      TRANSPOSED PV: hp^T = h^T @ attn^T. A-frags for ALL 4 mt PRELOADED into regs
    //      (within-wave WAR fence: hpB overlays this wave's own h_t slot).
    //      Packed b64 writes into per-head hpB; row 21 zeroed by col==5. ----
    {
        float4 fqa = *(const float4*)(f2 + w * F12S + quad * 8);
        float4 fqb = *(const float4*)(f2 + w * F12S + quad * 8 + 4);
        float fq[8] = {fqa.x, fqa.y, fqa.z, fqa.w, fqb.x, fqb.y, fqb.z, fqb.w};
        float fi0 = f1[w * F12S + col];
        const int am  = 16 + col;
        const int amc = (am < 21) ? am : 20;          // duplicate row 20; results masked
        float fi1 = f1[w * F12S + amc];
        float e0[8], e1[8];
        float s0 = 0.f, s1 = 0.f;
        #pragma unroll
        for (int j = 0; j < 8; j++) {
            float a0 = fi0 + fq[j]; a0 = fmaxf(a0, ALPHA * a0);
            float a1 = fi1 + fq[j]; a1 = fmaxf(a1, ALPHA * a1);
            float x0 = exp2_fast(a0);       // k>=21: a=-inf -> 0 exactly
            float x1 = exp2_fast(a1);
            e0[j] = x0; e1[j] = x1; s0 += x0; s1 += x1;
        }
        s0 += __shfl_xor(s0, 16); s0 += __shfl_xor(s0, 32);
        s1 += __shfl_xor(s1, 16); s1 += __shfl_xor(s1, 32);
        float inv0 = rcp_fast(s0), inv1 = rcp_fast(s1);
        uintx4 ua0, ua1;
        #pragma unroll
        for (int jj = 0; jj < 4; jj++) {
            ua0[jj] = pack2hi(e0[2*jj] * inv0, e0[2*jj+1] * inv0);
            ua1[jj] = pack2hi(e1[2*jj] * inv1, e1[2*jj+1] * inv1);
        }
        short8 aa0 = __builtin_bit_cast(short8, ua0);
        short8 aa1 = __builtin_bit_cast(short8, ua1);

        // preload all A-frags BEFORE any hpB write (reads alias the write region)
        short8 af[4];
        #pragma unroll
        for (int mt = 0; mt < 4; mt++)
            af[mt] = *(const short8*)(regA + w * HSLOT + (mt * 16 + col) * JPT + quad * 8);

        short* hb = regA + w * HSLOT;     // this head's hpB block
        #pragma unroll
        for (int mt = 0; mt < 4; mt++) {
            floatx4 z = {0.f, 0.f, 0.f, 0.f};
            floatx4 c0 = __builtin_amdgcn_mfma_f32_16x16x32_bf16(af[mt], aa0, z, 0, 0, 0);
            floatx4 c1 = __builtin_amdgcn_mfma_f32_16x16x32_bf16(af[mt], aa1, z, 0, 0, 0);
            // c0: hp rows 0..15 (row = col), features mt*16+quad*4 .. +3 (head-local)
            short* dst0 = hb + col * HPR + mt * 16 + quad * 4;
            *(uint2*)dst0 = make_uint2(pack2hi(elu(c0[0]), elu(c0[1])),
                                       pack2hi(elu(c0[2]), elu(c0[3])));
            // c1: hp rows 16..20 (col 0..4); col==5 writes the zero row 21; col>5 masked
            if (am < 21) {
                short* dst1 = hb + am * HPR + mt * 16 + quad * 4;
                *(uint2*)dst1 = make_uint2(pack2hi(elu(c1[0]), elu(c1[1])),
                                           pack2hi(elu(c1[2]), elu(c1[3])));
            } else if (am == 21) {
                *(uint2*)(hb + 21 * HPR + mt * 16 + quad * 4) = make_uint2(0u, 0u);
            }
        }
    }
    __syncthreads();                  // barrier #2

    // ---- stage 5 (MFMA): h2 = hp[21x256] @ Wo[256x64] (direct WoT loads — R6 form, the
    //      best-measured codegen; register prefetch across barriers spills or gets sunk).
    //      Reads hpB (all heads) first; mid-s5 barrier drains reads; then overlay-write
    //      h2 fp32 + h2_t bf16 into region A ----
    {
        floatx4 d0 = {0,0,0,0}, d1 = {0,0,0,0};
        #pragma unroll
        for (int s = 0; s < 8; s++) {
            const short* hb = regA + (s >> 1) * HSLOT;         // head = s/2
            const int f = (s & 1) * 32 + quad * 8;             // head-local feature
            short8 a0 = *(const short8*)(hb + col * HPR + f);
            short8 a1 = *(const short8*)(hb + rc  * HPR + f);
            short8 b  = *(const short8*)(WoT + (w * 16 + col) * 256 + s * 32 + quad * 8);
            d0 = __builtin_amdgcn_mfma_f32_16x16x32_bf16(a0, b, d0, 0, 0, 0);
            d1 = __builtin_amdgcn_mfma_f32_16x16x32_bf16(a1, b, d1, 0, 0, 0);
        }
        __syncthreads();              // barrier #3: hpB reads drained; region A free
        const int c = w * 16 + col;
        #pragma unroll
        for (int r = 0; r < 4; r++) {
            h2[(quad * 4 + r) * ROW2 + c] = d0[r];
            int row1 = 16 + quad * 4 + r;
            if (row1 < J) h2[row1 * ROW2 + c] = d1[r];
        }
        short* cb = h2_t + c * JPT;
        *(uint2*)(cb + quad * 4) = make_uint2(pack2hi(d0[0], d0[1]), pack2hi(d0[2], d0[3]));
        if (quad == 0)
            *(uint2*)(cb + 16) = make_uint2(pack2hi(d1[0], d1[1]), pack2hi(d1[2], d1[3]));
        else if (quad == 1)
            *(uint2*)(cb + 20) = make_uint2(pack2hi(d1[0], 0.f), 0u);
    }
    __syncthreads();                  // barrier #4 (LAST): h2/h2_t stable for the tail

    // Waves 0,1 are DONE — they retire here (frees their SIMD issue slots ~2 stages
    // early; no barriers follow, so the early exit is safe). The whole tail runs
    // redundantly on waves 2 and 3.
    if (w < 2) return;

    // ---- stage 6' (per-wave, redundant on waves 2,3 — replaces the old shared s6 +
    //      barrier): f1o[j] = h2[j][:].aoS[:64], f2o[j] = h2[j][:].aoS[64:] (log2e
    //      pre-folded); lanes 42..52 write the f2o -inf pads. Waves 2 and 3 write
    //      IDENTICAL values to the same addresses (benign), and each s8 wave reads only
    //      its OWN writes -> wave-local LDS ordering suffices, NO barrier. ----
    if (lane < 2 * J) {
        int wh = (lane >= J) ? 1 : 0;
        int j  = lane - wh * J;
        const float4* hrow = (const float4*)(h2 + j * ROW2);
        const float4* ap   = (const float4*)(aoS + wh * HD);
        float sa = 0.f, sb = 0.f;
        #pragma unroll
        for (int k = 0; k < 16; k += 2) {
            float4 h0 = hrow[k],     a0 = ap[k];
            float4 h1 = hrow[k + 1], a1 = ap[k + 1];
            sa += h0.x*a0.x + h0.y*a0.y + h0.z*a0.z + h0.w*a0.w;
            sb += h1.x*a1.x + h1.y*a1.y + h1.z*a1.z + h1.w*a1.w;
        }
        (wh ? f2o : f1o)[j] = sa + sb;
    } else if (lane < 53) {
        f2o[21 + (lane - 2 * J)] = -INFINITY;    // pads 21..31 for s8 softmax
    }

    // ---- stage 8 (waves 2,3; MFMA + register softmax, barrier-free): no valid-masking
    //      (f2o pads -inf); hp2 = attn2[21x21pad32] @ h2[21x64], ELU, in-wave log-softmax,
    //      store. Wave (w-2) = row-half mt; full r=0..3 epilogue per wave. ----
    {
        const int mt = w - 2;                              // row half: 0 -> rows 0..15, 1 -> 16..20
        const int arow = mt * 16 + col;
        const int ar = (arow < 21) ? arow : 20;            // clamped; rows masked at store

        float4 fqa = *(const float4*)(f2o + quad * 8);
        float4 fqb = *(const float4*)(f2o + quad * 8 + 4);
        float fq[8] = {fqa.x, fqa.y, fqa.z, fqa.w, fqb.x, fqb.y, fqb.z, fqb.w};
        float fi = f1o[ar];
        float ev[8];
        float ssum = 0.f;
        #pragma unroll
        for (int j = 0; j < 8; j++) {
            float e = fi + fq[j]; e = fmaxf(e, ALPHA * e);   // logits log2e-prescaled
            float x = exp2_fast(e);                          // k>=21 -> exact 0
            ev[j] = x; ssum += x;
        }
        ssum += __shfl_xor(ssum, 16); ssum += __shfl_xor(ssum, 32);
        float inv = rcp_fast(ssum);
        uintx4 ua;
        #pragma unroll
        for (int jj = 0; jj < 4; jj++)
            ua[jj] = pack2hi(ev[2*jj] * inv, ev[2*jj+1] * inv);
        short8 a = __builtin_bit_cast(short8, ua);

        floatx4 acc[4];
        #pragma unroll
        for (int nt = 0; nt < 4; nt++) {
            short8 b = *(const short8*)(h2_t + (nt * 16 + col) * JPT + quad * 8);
            floatx4 z = {0,0,0,0};
            acc[nt] = __builtin_amdgcn_mfma_f32_16x16x32_bf16(a, b, z, 0, 0, 0);
        }
        float* outp = out + pair * (size_t)(J * HD);
        #pragma unroll
        for (int rr = 0; rr < 4; rr++) {
            int row = mt * 16 + quad * 4 + rr;
            float v0 = elu(acc[0][rr]), v1 = elu(acc[1][rr]);
            float v2 = elu(acc[2][rr]), v3 = elu(acc[3][rr]);
            float s = __expf(v0) + __expf(v1) + __expf(v2) + __expf(v3);
            s += __shfl_xor(s, 1);
            s += __shfl_xor(s, 2);
            s += __shfl_xor(s, 4);
            s += __shfl_xor(s, 8);
            float ls = __logf(s);
            if (row < J) {
                outp[row * HD +      col] = v0 - ls;
                outp[row * HD + 16 + col] = v1 - ls;
                outp[row * HD + 32 + col] = v2 - ls;
                outp[row * HD + 48 + col] = v3 - ls;
            }
        }
    }
}

extern "C" void kernel_launch(void* const* d_in, const int* in_sizes, int n_in,
                              void* d_out, int out_size, void* d_ws, size_t ws_size,
                              hipStream_t stream) {
    const float* inp = (const float*)d_in[0];
    // d_in[1] = seq_start_end (int64) — unused by the reference computation
    const float* Wh  = (const float*)d_in[2];
    const float* ah  = (const float*)d_in[3];
    const float* Wo  = (const float*)d_in[4];
    const float* ao  = (const float*)d_in[5];
    float* outp = (float*)d_out;
    short* ws   = (short*)d_ws;   // 18560 shorts + 128 floats = 37632 B

    hipLaunchKernelGGL(preconv, dim3(73), dim3(256), 0, stream, Wo, Wh, ah, ao, ws);

    const int pairs = in_sizes[0] / (J * NH);  // 16384
    hipLaunchKernelGGL(gat_kernel, dim3(pairs), dim3(256), 0, stream,
                       inp, (const short*)ws, outp);
}

// Round 10
// 180.349 us; speedup vs baseline: 1.0604x; 1.0604x over previous
//
#include <hip/hip_runtime.h>
#include <hip/hip_bf16.h>
#include <math.h>

// Problem constants
#define J   21
#define NH  7
#define H   4
#define HD  64
#define ALPHA 0.2f
#define LOG2E 1.44269504f

// LDS strides (in elements)
#define JPA  40    // x_bf row stride (shorts)
#define JPT  24    // h_t / h2_t row stride (shorts)
#define HPR  72    // hpB per-head row stride (shorts); 72 sh = 144 B: 16B-aligned rows,
                   // stride 36 dwords == 4 mod 32 -> 2-way bank aliasing (free, m136)
#define HSLOT 1584 // per-head slot stride in region A (shorts) = max(h_t 64*24=1536, hpB 22*72=1584)
#define F12S 32    // f1/f2 per-head stride (floats); slots 21..31 = -inf pads
#define ROW2 68    // h2 fp32 row stride (floats)
#define WHTL_F 4012 // whtL base (floats): WhT staged copy [1024 f] + 16 f zero pad

// LDS map (floats), total 5052 f = 20208 B -> rounds to 20480 = 163840/8 -> 8 blocks/CU:
//   [0,3168)     region A (per-head slots of HSLOT=1584 shorts at w*1584):
//                s1 out: h_t head rows i=0..63 at w*1584 + i*24 (shorts); gap [1536,1584)
//                        per slot: first 8 shorts zeroed in s0 (s4 quad3 A-read spill of
//                        last h_t row). h_t j=21..23 are EXACT ZEROS (written so in s1 —
//                        R9 bug: leaving D rows 22..23 there stored x_bf-overrun garbage;
//                        fp32 read as bf16 can be NaN, and s4's NaN*0=NaN poisoned hp)
//                s4 out (overlay, SAME head slot -> no cross-wave race; within-wave WAR
//                        solved by preloading all 4 A-frags before any write):
//                        hpB row r at w*1584 + r*72, r=0..21 (row 21 zeroed by col==5 lanes)
//                s5 out (overlay after mid-s5 barrier, all hpB reads drained):
//                        h2[21][ROW2] fp32 @ A+0 (1428 f); h2_t[64][JPT] shorts @ float 1432
//                        (ends 2200; s8 quad3 spill reads A[2200..2202) = finite leftovers x 0)
//   [3168,3608)  x_bf[22][JPA] shorts (s0: zero pass covers shorts [8,40) of rows 0..20 +
//                row 21; scatter covers [0,7); 21 threads zero short 7 -> ONE barrier);
//                s1 32x32 A-reads for m=22..31 overrun into xs_raw/f1 (possibly NaN as
//                bf16 — SAFE: their D rows 22..31 are suppressed or overwritten w/ zeros);
//                dead after s1 -> f1o@[3168,3189), f2o@[3192,3224) overlay
//                (s6 out / s8 in; f2o 21..31 = -inf)
//   [3608,3755)  xs_raw[147] fp32 (s0 out / s1b in)
//   [3756,3884)  f1[4][F12S] (s1b out / s4 in)
//   [3884,4012)  f2[4][F12S] (s1b out / s4 in; 21..31 = -inf, set in s0)
//   [4012,5036)  whtL[2048 shorts]: WhT staged via global_load_lds in s0 (s1 B-frags,
//                k=0..7 per feature; feature n=7 slot is zero from preconv)
//   [5036,5052)  ZERO pad (s0): 16B @5036 is the s1 B-frag for lanes>=32 (k=8..15 = 0 —
//                only 7 input dims exist). Must be EXACT zeros.
#define LDS_FLOATS 5052

typedef __attribute__((ext_vector_type(8))) short short8;
typedef __attribute__((ext_vector_type(4))) float floatx4;
typedef __attribute__((ext_vector_type(16))) float floatx16;
typedef __attribute__((ext_vector_type(4))) unsigned uintx4;

typedef __attribute__((address_space(1))) const void gas_void;
typedef __attribute__((address_space(3))) void las_void;

static __device__ __forceinline__ short f2bf(float f) {          // RNE (preconv only)
    __hip_bfloat16 h = __float2bfloat16(f);
    return __builtin_bit_cast(short, h);
}
static __device__ __forceinline__ short hi16(float f) {          // truncating bf16 (cheap)
    return (short)(__builtin_bit_cast(unsigned, f) >> 16);
}
static __device__ __forceinline__ unsigned pack2hi(float lo, float hi) {
    return __builtin_amdgcn_perm(__builtin_bit_cast(unsigned, hi),
                                 __builtin_bit_cast(unsigned, lo), 0x07060302u);
}
static __device__ __forceinline__ float elu(float a) {
    return (a > 0.f) ? a : (__expf(a) - 1.f);
}

#if __has_builtin(__builtin_amdgcn_exp2f)
static __device__ __forceinline__ float exp2_fast(float x) { return __builtin_amdgcn_exp2f(x); }
#else
static __device__ __forceinline__ float exp2_fast(float x) { return exp2f(x); }
#endif
#if __has_builtin(__builtin_amdgcn_rcpf)
static __device__ __forceinline__ float rcp_fast(float x) { return __builtin_amdgcn_rcpf(x); }
#else
static __device__ __forceinline__ float rcp_fast(float x) { return 1.f / x; }
#endif

// ---- pre-kernel: bf16 weight tables + wha fusion + log2e-prescaled ao ----
// ws shorts: [0,16384)      WoT[n=64][k=256] = bf(Wo[k][n])
//            [16384,18432)  WhT[(h*64+d)][8] : n<7 -> bf(Wh[h][n][d]), n=7 -> 0
//            [18432,18560)  wha[h][2][8] fp32 : wha[h][s][n] = LOG2E * sum_d Wh[h][n][d]*ah[h][s*64+d]
//            [18560,18816)  aoS[128] fp32 = ao * LOG2E
__global__ void preconv(const float* __restrict__ Wo, const float* __restrict__ Wh,
                        const float* __restrict__ ah, const float* __restrict__ ao,
                        short* __restrict__ ws) {
    int t = blockIdx.x * 256 + threadIdx.x;
    if (t < 16384) {
        int n = t >> 8, k = t & 255;
        ws[t] = f2bf(Wo[k * HD + n]);
    } else if (t < 18432) {
        int i = t - 16384;
        int hh = i >> 9, d = (i >> 3) & 63, n = i & 7;
        ws[t] = (n < 7) ? f2bf(Wh[(hh * NH + n) * HD + d]) : (short)0;
    } else if (t < 18496) {
        int i = t - 18432;                 // 0..63
        int hh = i >> 4, s = (i >> 3) & 1, n = i & 7;
        float acc = 0.f;
        if (n < 7) {
            for (int d = 0; d < HD; d++)
                acc += Wh[(hh * NH + n) * HD + d] * ah[hh * 2 * HD + s * HD + d];
        }
        ((float*)(ws + 18432))[i] = acc * LOG2E;
    } else if (t < 18624) {
        int i = t - 18496;                 // 0..127
        ((float*)(ws + 18560))[i] = ao[i] * LOG2E;
    }
}

__global__ __launch_bounds__(256, 8)
void gat_kernel(const float* __restrict__ inp,
                const short* __restrict__ ws,   // WoT + WhT + wha + aoS
                float* __restrict__ out)
{
    __shared__ __align__(16) float smem[LDS_FLOATS];
    short* regA   = (short*)smem;                 // h_t / hpB / h2_t home
    float* h2     = smem;                         // [21][ROW2] fp32 (post mid-s5 overlay)
    short* h2_t   = (short*)(smem + 1432);        // [64][JPT]  (post mid-s5 overlay)
    float* f1o    = smem + 3168;                  // post-s5 overlays of x_bf region
    float* f2o    = smem + 3192;
    float* f1     = smem + 3756;                  // [4][F12S]
    float* f2     = smem + 3884;                  // [4][F12S]
    short* whtL   = (short*)(smem + WHTL_F);      // [2048] staged WhT

    const short* WoT  = ws;
    const short* WhT  = ws + 16384;
    const float* whaF = (const float*)(ws + 18432);
    const float* aoS  = (const float*)(ws + 18560);

    const int t    = threadIdx.x;
    const int w    = t >> 6;          // wave = head = tile index
    const int lane = t & 63;
    const int quad = lane >> 4;
    const int col  = lane & 15;
    const int rc   = (16 + col < 21) ? (16 + col) : 21;   // clamped M1 row (row 21 zeroed)

    const size_t pair = blockIdx.x;
    const float* ip = inp + pair * (size_t)(J * NH);

    // ---- stage 0 (ONE barrier): issue input load + async WhT->LDS stage first (both
    //      latencies hide under the zero/pad writes; the barrier's vmcnt(0) drains the
    //      async stage). Zero pass covers only x_bf shorts [8,40) per row (+row 21) so
    //      the scatter (shorts [0,7)) and k=7 zeroing write disjoint addresses. ----
    float v = 0.f;
    if (t < J * NH) v = ip[t];
    __builtin_amdgcn_global_load_lds(
        (gas_void*)(WhT + (size_t)(w * 64 + lane) * 8),
        (las_void*)(whtL + w * 512), 16, 0, 0);

    {
        floatx4 z4 = {0.f, 0.f, 0.f, 0.f};
        if (t < 84) {                 // x_bf rows 0..20, shorts [8,40) = 4 float4/row
            int j = t >> 2, q = t & 3;
            *(floatx4*)(smem + 3168 + j * 20 + 4 + q * 4) = z4;
        } else if (t < 89) {          // x_bf row 21 entire (5 float4)
            *(floatx4*)(smem + 3168 + 420 + (t - 84) * 4) = z4;
        } else if (t < 105) {         // region-A slot gaps (s4 quad3 A-read spill), 4 f/head
            int i = t - 89;
            smem[(i >> 2) * (HSLOT / 2) + (1536 / 2) + (i & 3)] = 0.f;
        } else if (t < 149) {         // f2 -inf softmax pads 21..31, 4 heads
            int i = t - 105;
            int hh = i / 11, jj = i - hh * 11;
            f2[hh * F12S + 21 + jj] = -INFINITY;
        } else if (t < 165) {         // ZERO pad @5036 (s1 lane>=32 B-frag, k=8..15 = 0)
            smem[WHTL_F + 1024 + (t - 149)] = 0.f;
        }
    }
    if (t < J * NH) {                 // scatter: x_bf shorts [0,7) + xs_raw
        int j, k;
        if (t < 63)       { j = t / 3;        k = t % 3; }
        else if (t < 126) { j = (t - 63) / 3; k = 3 + (t - 63) % 3; }
        else              { j = t - 126;      k = 6; }
        ((short*)(smem + 3168))[j * JPA + k] = hi16(v);
        smem[3608 + t] = v;
    } else if (t < 168) {             // x_bf short 7 zero, rows 0..20
        ((short*)(smem + 3168))[(t - 147) * JPA + 7] = 0;
    }
    __syncthreads();                  // barrier #1

    // ---- stage 1 (ONE 32x32x16 MFMA per 32-feature N-tile): h = x[21x7pad] @ Wh_head[7x64]
    //      -> h_t bf16 (B-layout, per-head slot at w*HSLOT).
    //      A[m][k]: m=lane&31 (j row; m=21 zeros, m=22..31 overrun — MAY BE NaN as bf16,
    //               rows discarded/zeroed), k=8*(lane>>5)+e (x_bf cols; k>=7 zeros).
    //      B[k][n]: n=lane&31 (feature), k=8*(lane>>5)+e: lanes<32 read whtL k=0..7,
    //               lanes>=32 read the 16B ZERO pad (k=8..15 = 0).
    //      D: col=lane&31 (feature), row=(reg&3)+8*(reg>>2)+4*(lane>>5) (=j) [m74/m101].
    //      Writes: half=0 -> j{0-3,8-11,16-19}; half=1 -> j{4-7,12-15,20-23} with j=21..23
    //      FORCED ZERO (R9 fix: D rows 22..23 are overrun garbage, possibly NaN — s4 would
    //      compute NaN*0=NaN); reg-quad 3 (j>=24) suppressed. j=0..23 covered exactly once.
    //      1b: f1/f2 = x @ wha (fp32, log2e prescaled), spread over t<84. ----
    {
        const short* x_bf = (const short*)(smem + 3168);
        const int half = lane >> 5;
        const int n32  = lane & 31;
        short8 xa = *(const short8*)(x_bf + n32 * JPA + half * 8);
        const short* zpad = (const short*)(smem + WHTL_F + 1024);
        #pragma unroll
        for (int Nt = 0; Nt < 2; Nt++) {
            const short* bptr = half ? zpad
                                     : (const short*)(whtL + ((w * 64 + Nt * 32 + n32) << 3));
            short8 bb = *(const short8*)bptr;
            floatx16 z16 = {0.f,0.f,0.f,0.f,0.f,0.f,0.f,0.f,
                            0.f,0.f,0.f,0.f,0.f,0.f,0.f,0.f};
            floatx16 d = __builtin_amdgcn_mfma_f32_32x32x16_bf16(xa, bb, z16, 0, 0, 0);
            short* colbase = regA + w * HSLOT + (Nt * 32 + n32) * JPT;
            #pragma unroll
            for (int rq = 0; rq < 3; rq++) {
                int j0 = rq * 8 + half * 4;
                if (half == 1 && rq == 2) {
                    // j 20..23: row 20 value; rows 21,22,23 EXACT ZERO (see header)
                    *(uint2*)(colbase + j0) = make_uint2(pack2hi(d[8], 0.f), 0u);
                } else {
                    *(uint2*)(colbase + j0) = make_uint2(
                        pack2hi(d[rq*4+0], d[rq*4+1]), pack2hi(d[rq*4+2], d[rq*4+3]));
                }
            }
        }
        if (t < 84) {
            int hh = t / 21, j = t - hh * 21;
            const float* xr = smem + 3608;    // xs_raw
            float x0 = xr[j*3+0], x1 = xr[j*3+1], x2 = xr[j*3+2];
            float x3 = xr[63+j*3+0], x4 = xr[63+j*3+1], x5 = xr[63+j*3+2];
            float x6 = xr[126+j];
            const float* wp = whaF + hh * 16;
            f1[hh * F12S + j] = x0*wp[0] + x1*wp[1] + x2*wp[2] + x3*wp[3]
                              + x4*wp[4] + x5*wp[5] + x6*wp[6];
            f2[hh * F12S + j] = x0*wp[8] + x1*wp[9] + x2*wp[10] + x3*wp[11]
                              + x4*wp[12] + x5*wp[13] + x6*wp[14];
        }
    }
    __syncthreads();                  // barrier #2

    // ---- stage 4 (MFMA + register softmax): no valid-masking (f2 pads -inf -> exp2 -> 0).
    //      TRANSPOSED PV: hp^T = h^T @ attn^T. A-frags for ALL 4 mt PRELOADED into regs
    //      (within-wave WAR fence: hpB overlays this wave's own h_t slot).
    //      Packed b64 writes into per-head hpB; row 21 zeroed by col==5. ----
    {
        float4 fqa = *(const float4*)(f2 + w * F12S + quad * 8);
        float4 fqb = *(const float4*)(f2 + w * F12S + quad * 8 + 4);
        float fq[8] = {fqa.x, fqa.y, fqa.z, fqa.w, fqb.x, fqb.y, fqb.z, fqb.w};
        float fi0 = f1[w * F12S + col];
        const int am  = 16 + col;
        const int amc = (am < 21) ? am : 20;          // duplicate row 20; results masked
        float fi1 = f1[w * F12S + amc];
        float e0[8], e1[8];
        float s0 = 0.f, s1 = 0.f;
        #pragma unroll
        for (int j = 0; j < 8; j++) {
            float a0 = fi0 + fq[j]; a0 = fmaxf(a0, ALPHA * a0);
            float a1 = fi1 + fq[j]; a1 = fmaxf(a1, ALPHA * a1);
            float x0 = exp2_fast(a0);       // k>=21: a=-inf -> 0 exactly
            float x1 = exp2_fast(a1);
            e0[j] = x0; e1[j] = x1; s0 += x0; s1 += x1;
        }
        s0 += __shfl_xor(s0, 16); s0 += __shfl_xor(s0, 32);
        s1 += __shfl_xor(s1, 16); s1 += __shfl_xor(s1, 32);
        float inv0 = rcp_fast(s0), inv1 = rcp_fast(s1);
        uintx4 ua0, ua1;
        #pragma unroll
        for (int jj = 0; jj < 4; jj++) {
            ua0[jj] = pack2hi(e0[2*jj] * inv0, e0[2*jj+1] * inv0);
            ua1[jj] = pack2hi(e1[2*jj] * inv1, e1[2*jj+1] * inv1);
        }
        short8 aa0 = __builtin_bit_cast(short8, ua0);
        short8 aa1 = __builtin_bit_cast(short8, ua1);

        // preload all A-frags BEFORE any hpB write (reads alias the write region)
        short8 af[4];
        #pragma unroll
        for (int mt = 0; mt < 4; mt++)
            af[mt] = *(const short8*)(regA + w * HSLOT + (mt * 16 + col) * JPT + quad * 8);

        short* hb = regA + w * HSLOT;     // this head's hpB block
        #pragma unroll
        for (int mt = 0; mt < 4; mt++) {
            floatx4 z = {0.f, 0.f, 0.f, 0.f};
            floatx4 c0 = __builtin_amdgcn_mfma_f32_16x16x32_bf16(af[mt], aa0, z, 0, 0, 0);
            floatx4 c1 = __builtin_amdgcn_mfma_f32_16x16x32_bf16(af[mt], aa1, z, 0, 0, 0);
            // c0: hp rows 0..15 (row = col), features mt*16+quad*4 .. +3 (head-local)
            short* dst0 = hb + col * HPR + mt * 16 + quad * 4;
            *(uint2*)dst0 = make_uint2(pack2hi(elu(c0[0]), elu(c0[1])),
                                       pack2hi(elu(c0[2]), elu(c0[3])));
            // c1: hp rows 16..20 (col 0..4); col==5 writes the zero row 21; col>5 masked
            if (am < 21) {
                short* dst1 = hb + am * HPR + mt * 16 + quad * 4;
                *(uint2*)dst1 = make_uint2(pack2hi(elu(c1[0]), elu(c1[1])),
                                           pack2hi(elu(c1[2]), elu(c1[3])));
            } else if (am == 21) {
                *(uint2*)(hb + 21 * HPR + mt * 16 + quad * 4) = make_uint2(0u, 0u);
            }
        }
    }
    __syncthreads();                  // barrier #3

    // ---- stage 5 (MFMA): h2 = hp[21x256] @ Wo[256x64] (direct WoT loads — best-measured
    //      codegen). Reads hpB (all heads) first; mid-s5 barrier drains reads; then
    //      overlay-write h2 fp32 + h2_t bf16 into region A ----
    {
        floatx4 d0 = {0,0,0,0}, d1 = {0,0,0,0};
        #pragma unroll
        for (int s = 0; s < 8; s++) {
            const short* hb = regA + (s >> 1) * HSLOT;         // head = s/2
            const int f = (s & 1) * 32 + quad * 8;             // head-local feature
            short8 a0 = *(const short8*)(hb + col * HPR + f);
            short8 a1 = *(const short8*)(hb + rc  * HPR + f);
            short8 b  = *(const short8*)(WoT + (w * 16 + col) * 256 + s * 32 + quad * 8);
            d0 = __builtin_amdgcn_mfma_f32_16x16x32_bf16(a0, b, d0, 0, 0, 0);
            d1 = __builtin_amdgcn_mfma_f32_16x16x32_bf16(a1, b, d1, 0, 0, 0);
        }
        __syncthreads();              // barrier #4: hpB reads drained; region A free
        const int c = w * 16 + col;
        #pragma unroll
        for (int r = 0; r < 4; r++) {
            h2[(quad * 4 + r) * ROW2 + c] = d0[r];
            int row1 = 16 + quad * 4 + r;
            if (row1 < J) h2[row1 * ROW2 + c] = d1[r];
        }
        short* cb = h2_t + c * JPT;
        *(uint2*)(cb + quad * 4) = make_uint2(pack2hi(d0[0], d0[1]), pack2hi(d0[2], d0[3]));
        if (quad == 0)
            *(uint2*)(cb + 16) = make_uint2(pack2hi(d1[0], d1[1]), pack2hi(d1[2], d1[3]));
        else if (quad == 1)
            *(uint2*)(cb + 20) = make_uint2(pack2hi(d1[0], 0.f), 0u);
    }
    __syncthreads();                  // barrier #5: h2/h2_t stable

    // ---- stage 6: f1o[j] = h2[j][:].aoS[:64], f2o[j] = h2[j][:].aoS[64:]  (log2e pre-folded)
    //      4 threads per dot (16 MACs each) + 2-level shfl reduce; also set f2o -inf pads ----
    if (t < 4 * 2 * J) {
        int which = (t >= 4 * J) ? 1 : 0;
        int r2 = t - which * 4 * J;
        int j = r2 >> 2, seg = r2 & 3;
        const float4* hrow = (const float4*)(h2 + j * ROW2) + seg * 4;
        const float4* ap   = (const float4*)(aoS + which * HD) + seg * 4;
        float sacc = 0.f;
        #pragma unroll
        for (int k = 0; k < 4; k++) {
            float4 hv = hrow[k], av = ap[k];
            sacc += hv.x*av.x + hv.y*av.y + hv.z*av.z + hv.w*av.w;
        }
        sacc += __shfl_xor(sacc, 1);
        sacc += __shfl_xor(sacc, 2);
        if (seg == 0) {
            if (which == 0) f1o[j] = sacc; else f2o[j] = sacc;
        }
    } else if (t < 179) {
        f2o[21 + (t - 168)] = -INFINITY;                  // pads 21..31 for s8 softmax
    }
    __syncthreads();                  // barrier #6 (LAST)
    // Waves 2,3 are done: s8's softmax+MFMA depend only on mt=w&1 (f1o/f2o/h2_t are
    // head-independent), so waves 2,3 would be exact duplicates of 0,1. They exit here
    // (safe: no further barriers). Waves 0,1 cover all 4 accumulator rows below.
    if (w >= 2) return;

    // ---- stage 8 (waves 0,1; MFMA + register softmax, barrier-free): no valid-masking
    //      (f2o pads -inf); hp2 = attn2[21x21pad32] @ h2[21x64], ELU, in-wave log-softmax,
    //      store. Wave w = row-half mt; full r=0..3 epilogue per wave. ----
    {
        const int mt = w;                                  // row half: 0 -> rows 0..15, 1 -> 16..20
        const int arow = mt * 16 + col;
        const int ar = (arow < 21) ? arow : 20;            // clamped; rows masked at store

        float4 fqa = *(const float4*)(f2o + quad * 8);
        float4 fqb = *(const float4*)(f2o + quad * 8 + 4);
        float fq[8] = {fqa.x, fqa.y, fqa.z, fqa.w, fqb.x, fqb.y, fqb.z, fqb.w};
        float fi = f1o[ar];
        float ev[8];
        float ssum = 0.f;
        #pragma unroll
        for (int j = 0; j < 8; j++) {
            float e = fi + fq[j]; e = fmaxf(e, ALPHA * e);   // logits log2e-prescaled
            float x = exp2_fast(e);                          // k>=21 -> exact 0
            ev[j] = x; ssum += x;
        }
        ssum += __shfl_xor(ssum, 16); ssum += __shfl_xor(ssum, 32);
        float inv = rcp_fast(ssum);
        uintx4 ua;
        #pragma unroll
        for (int jj = 0; jj < 4; jj++)
            ua[jj] = pack2hi(ev[2*jj] * inv, ev[2*jj+1] * inv);
        short8 a = __builtin_bit_cast(short8, ua);

        floatx4 acc[4];
        #pragma unroll
        for (int nt = 0; nt < 4; nt++) {
            short8 b = *(const short8*)(h2_t + (nt * 16 + col) * JPT + quad * 8);
            floatx4 z = {0,0,0,0};
            acc[nt] = __builtin_amdgcn_mfma_f32_16x16x32_bf16(a, b, z, 0, 0, 0);
        }
        float* outp = out + pair * (size_t)(J * HD);
        #pragma unroll
        for (int rr = 0; rr < 4; rr++) {
            int row = mt * 16 + quad * 4 + rr;
            float v0 = elu(acc[0][rr]), v1 = elu(acc[1][rr]);
            float v2 = elu(acc[2][rr]), v3 = elu(acc[3][rr]);
            float s = __expf(v0) + __expf(v1) + __expf(v2) + __expf(v3);
            s += __shfl_xor(s, 1);
            s += __shfl_xor(s, 2);
            s += __shfl_xor(s, 4);
            s += __shfl_xor(s, 8);
            float ls = __logf(s);
            if (row < J) {
                outp[row * HD +      col] = v0 - ls;
                outp[row * HD + 16 + col] = v1 - ls;
                outp[row * HD + 32 + col] = v2 - ls;
                outp[row * HD + 48 + col] = v3 - ls;
            }
        }
    }
}

extern "C" void kernel_launch(void* const* d_in, const int* in_sizes, int n_in,
                              void* d_out, int out_size, void* d_ws, size_t ws_size,
                              hipStream_t stream) {
    const float* inp = (const float*)d_in[0];
    // d_in[1] = seq_start_end (int64) — unused by the reference computation
    const float* Wh  = (const float*)d_in[2];
    const float* ah  = (const float*)d_in[3];
    const float* Wo  = (const float*)d_in[4];
    const float* ao  = (const float*)d_in[5];
    float* outp = (float*)d_out;
    short* ws   = (short*)d_ws;   // 18560 shorts + 128 floats = 37632 B

    hipLaunchKernelGGL(preconv, dim3(73), dim3(256), 0, stream, Wo, Wh, ah, ao, ws);

    const int pairs = in_sizes[0] / (J * NH);  // 16384
    hipLaunchKernelGGL(gat_kernel, dim3(pairs), dim3(256), 0, stream,
                       inp, (const short*)ws, outp);
}